// Round 5
// baseline (357.780 us; speedup 1.0000x reference)
//
#include <hip/hip_runtime.h>
#include <hip/hip_bf16.h>
#include <hip/hip_cooperative_groups.h>

namespace cg = cooperative_groups;

// Chamfer min-matching loss, B=8, P=4096, D=2, fp32 — single cooperative dispatch.
// d2(q,g) = |q|^2 + (|g|^2 - 2 q.g). Phase 1: each block computes min over its
// base chunk for 2048 queries (plain stores, one writer per slot). grid.sync().
// Phase 2a: cross-chunk min + sqrt + block partial sums. grid.sync().
// Phase 2b: block 0 sums partials, writes out. No atomics, no ws init needed.

#define NB    8
#define NP    4096
#define QPT   8
#define NC    32
#define NPC   2               // NP / (256*QPT)
#define GRID  (NC * NPC * NB * 2)   // 1024
#define CHUNK (NP / NC)       // 128

typedef float f32x4 __attribute__((ext_vector_type(4)));

__global__ __launch_bounds__(256, 4) void chamferFused(const float* __restrict__ pred,
                                                       const float* __restrict__ gt,
                                                       float* __restrict__ pm,
                                                       float* __restrict__ bsum,
                                                       float* __restrict__ out) {
    __shared__ __align__(16) float shx[CHUNK];
    __shared__ __align__(16) float shy[CHUNK];
    __shared__ __align__(16) float sc[CHUNK];
    __shared__ float red[256];
    __shared__ float wsum[4];

    cg::grid_group grid = cg::this_grid();

    int bid = blockIdx.x;
    int t   = threadIdx.x;

    // ---- Phase 1: partial mins ----
    {
        int gc  = bid % NC;
        int pc  = (bid / NC) % NPC;
        int b   = (bid / (NC * NPC)) % NB;
        int dir = bid / (NC * NPC * NB);

        const float* query = dir ? gt : pred;
        const float* base  = dir ? pred : gt;

        const float2* base2 = (const float2*)base + (size_t)b * NP + gc * CHUNK;
        if (t < CHUNK) {
            float2 g = base2[t];
            shx[t] = -2.0f * g.x;
            shy[t] = -2.0f * g.y;
            sc[t]  = g.x * g.x + g.y * g.y;
        }
        __syncthreads();

        const float2* query2 = (const float2*)query + (size_t)b * NP + pc * (256 * QPT);
        float px[QPT], py[QPT], p2[QPT], m[QPT];
#pragma unroll
        for (int k = 0; k < QPT; ++k) {
            float2 q = query2[t + k * 256];
            px[k] = q.x; py[k] = q.y;
            p2[k] = q.x * q.x + q.y * q.y;
            m[k]  = 3.402823466e+38f;
        }

        const f32x4* hx4 = (const f32x4*)shx;
        const f32x4* hy4 = (const f32x4*)shy;
        const f32x4* cc4 = (const f32x4*)sc;

#pragma unroll 4
        for (int j = 0; j < CHUNK / 4; ++j) {
            f32x4 hx = hx4[j], hy = hy4[j], cc = cc4[j];
#pragma unroll
            for (int k = 0; k < QPT; ++k) {
                float d0 = fmaf(px[k], hx.x, fmaf(py[k], hy.x, cc.x));
                float d1 = fmaf(px[k], hx.y, fmaf(py[k], hy.y, cc.y));
                float d2 = fmaf(px[k], hx.z, fmaf(py[k], hy.z, cc.z));
                float d3 = fmaf(px[k], hx.w, fmaf(py[k], hy.w, cc.w));
                m[k] = fminf(fminf(m[k], d0), d1);   // v_min3_f32
                m[k] = fminf(fminf(m[k], d2), d3);
            }
        }

        // pm[((dir*NB+b)*NC + gc)*NP + pc*2048 + t + k*256] — one writer each
        float* slot = pm + (((size_t)dir * NB + b) * NC + gc) * NP + pc * (256 * QPT) + t;
#pragma unroll
        for (int k = 0; k < QPT; ++k) slot[k * 256] = m[k] + p2[k];
    }

    __threadfence();
    grid.sync();

    // ---- Phase 2a: cross-chunk min + sqrt + block partial sum ----
    {
        // slot s = bid*64 + (t&63); 4 thread-groups each min 8 of the 32 chunks
        int s    = bid * 64 + (t & 63);
        int dirb = s >> 12;            // dir*NB + b
        int q    = s & (NP - 1);
        int cg4  = t >> 6;             // 0..3

        const float* p = pm + ((size_t)dirb * NC + cg4 * 8) * NP + q;
        float mv = p[0];
#pragma unroll
        for (int c = 1; c < 8; ++c) mv = fminf(mv, p[(size_t)c * NP]);
        red[cg4 * 64 + (t & 63)] = mv;
        __syncthreads();

        if (t < 64) {
            float m4 = fminf(fminf(red[t], red[64 + t]),
                             fminf(red[128 + t], red[192 + t]));
            float v = sqrtf(fmaxf(m4, 1e-12f));
#pragma unroll
            for (int o = 32; o > 0; o >>= 1) v += __shfl_down(v, o, 64);
            if (t == 0) bsum[bid] = v;
        }
    }

    __threadfence();
    grid.sync();

    // ---- Phase 2b: block 0 reduces 1024 partials ----
    if (bid == 0) {
        f32x4 v = ((const f32x4*)bsum)[t];
        float s = (v.x + v.y) + (v.z + v.w);
#pragma unroll
        for (int o = 32; o > 0; o >>= 1) s += __shfl_down(s, o, 64);
        int lane = t & 63, w = t >> 6;
        if (lane == 0) wsum[w] = s;
        __syncthreads();
        if (t == 0)
            *out = ((wsum[0] + wsum[1]) + (wsum[2] + wsum[3])) * (0.5f / (float)(NB * NP));
    }
}

extern "C" void kernel_launch(void* const* d_in, const int* in_sizes, int n_in,
                              void* d_out, int out_size, void* d_ws, size_t ws_size,
                              hipStream_t stream) {
    const float* pred = (const float*)d_in[0];
    const float* gt   = (const float*)d_in[1];
    float*       out  = (float*)d_out;
    float*       pm   = (float*)d_ws;                       // 2*8*32*4096 f32 = 8 MiB
    float*       bsum = pm + (size_t)2 * NB * NC * NP;      // 1024 f32

    (void)in_sizes; (void)n_in; (void)out_size; (void)ws_size;

    void* args[] = { (void*)&pred, (void*)&gt, (void*)&pm, (void*)&bsum, (void*)&out };
    hipLaunchCooperativeKernel((void*)chamferFused, dim3(GRID), dim3(256), args, 0, stream);
}

// Round 6
// 29.091 us; speedup vs baseline: 12.2988x; 12.2988x over previous
//
#include <hip/hip_runtime.h>

// Chamfer min-matching loss, B=8, P=4096, D=2, fp32.
// d2(q,g) = |q|^2 + (|g|^2 - 2 q.g). Per base point: hx=-2gx, hy=-2gy, c=|g|^2
// staged in LDS. Inner: 2 fma + 0.5 min3 per pair. All per-query state in
// NAMED SCALARS (no arrays -> no scratch; R5 post-mortem: VGPR=28 = spill).
// QPT=16 queries/thread: 3 ds_read_b128 per 64 pairs -> LDS well under VALU.

#define NB    8
#define NP    4096
#define NC    32
#define CHUNK (NP / NC)        // 128
#define GRIDA (2 * NB * NC)    // 512 blocks

typedef float f32x4 __attribute__((ext_vector_type(4)));

#define FOREACH_Q(M) M(0) M(1) M(2) M(3) M(4) M(5) M(6) M(7) \
                     M(8) M(9) M(10) M(11) M(12) M(13) M(14) M(15)

__global__ __launch_bounds__(256) void chamferA(const float* __restrict__ pred,
                                                const float* __restrict__ gt,
                                                float* __restrict__ pm,
                                                float* __restrict__ out) {
    __shared__ __align__(16) float shx[CHUNK];
    __shared__ __align__(16) float shy[CHUNK];
    __shared__ __align__(16) float sc[CHUNK];

    // zero the accumulator; stream order puts this before chamferB's atomics.
    if (blockIdx.x == 0 && threadIdx.x == 0) *out = 0.0f;

    int bid = blockIdx.x;
    int gc  = bid % NC;  bid /= NC;
    int b   = bid & 7;
    int dir = bid >> 3;            // 0: query=pred base=gt ; 1: query=gt base=pred

    const float* query = dir ? gt : pred;
    const float* base  = dir ? pred : gt;

    const float2* base2 = (const float2*)base + (size_t)b * NP + gc * CHUNK;
    int t = threadIdx.x;
    if (t < CHUNK) {
        float2 g = base2[t];
        shx[t] = -2.0f * g.x;
        shy[t] = -2.0f * g.y;
        sc[t]  = g.x * g.x + g.y * g.y;
    }
    __syncthreads();

    const float2* query2 = (const float2*)query + (size_t)b * NP;
    const float INF = 3.402823466e+38f;

#define DECLQ(k) float px##k, py##k, m##k = INF; \
    { float2 q_ = query2[t + (k) * 256]; px##k = q_.x; py##k = q_.y; }
    FOREACH_Q(DECLQ)
#undef DECLQ

    const f32x4* hx4 = (const f32x4*)shx;
    const f32x4* hy4 = (const f32x4*)shy;
    const f32x4* cc4 = (const f32x4*)sc;

#pragma unroll 4
    for (int j = 0; j < CHUNK / 4; ++j) {
        f32x4 hx = hx4[j], hy = hy4[j], cc = cc4[j];
#define STEP(k) { \
        float d0_ = fmaf(px##k, hx.x, fmaf(py##k, hy.x, cc.x)); \
        float d1_ = fmaf(px##k, hx.y, fmaf(py##k, hy.y, cc.y)); \
        float d2_ = fmaf(px##k, hx.z, fmaf(py##k, hy.z, cc.z)); \
        float d3_ = fmaf(px##k, hx.w, fmaf(py##k, hy.w, cc.w)); \
        m##k = fminf(fminf(m##k, d0_), d1_);   /* v_min3_f32 */ \
        m##k = fminf(fminf(m##k, d2_), d3_); }
        FOREACH_Q(STEP)
#undef STEP
    }

    float* slot = pm + (((size_t)dir * NB + b) * NC + gc) * NP + t;
#define STORE(k) slot[(k) * 256] = fmaf(px##k, px##k, fmaf(py##k, py##k, m##k));
    FOREACH_Q(STORE)
#undef STORE
}

__global__ __launch_bounds__(256) void chamferB(const float* __restrict__ pm,
                                                float* __restrict__ out) {
    int idx  = blockIdx.x * 256 + threadIdx.x;   // 0 .. 2*NB*NP-1
    int dirb = idx >> 12;                        // dir*NB + b
    int q    = idx & (NP - 1);

    const float* p = pm + ((size_t)dirb * NC) * NP + q;
    float mv = p[0];
#pragma unroll
    for (int c = 1; c < NC; ++c) mv = fminf(mv, p[(size_t)c * NP]);

    float v = sqrtf(fmaxf(mv, 1e-12f));

#pragma unroll
    for (int o = 32; o > 0; o >>= 1) v += __shfl_down(v, o, 64);

    __shared__ float wsum[4];
    int lane = threadIdx.x & 63;
    int w    = threadIdx.x >> 6;
    if (lane == 0) wsum[w] = v;
    __syncthreads();
    if (threadIdx.x == 0) {
        float sblk = (wsum[0] + wsum[1]) + (wsum[2] + wsum[3]);
        atomicAdd(out, sblk * (0.5f / (float)(NB * NP)));
    }
}

extern "C" void kernel_launch(void* const* d_in, const int* in_sizes, int n_in,
                              void* d_out, int out_size, void* d_ws, size_t ws_size,
                              hipStream_t stream) {
    const float* pred = (const float*)d_in[0];
    const float* gt   = (const float*)d_in[1];
    float*       out  = (float*)d_out;
    float*       pm   = (float*)d_ws;            // 2*8*32*4096 f32 = 8 MiB

    (void)in_sizes; (void)n_in; (void)out_size; (void)ws_size;

    chamferA<<<GRIDA, 256, 0, stream>>>(pred, gt, pm, out);
    chamferB<<<(2 * NB * NP) / 256, 256, 0, stream>>>(pm, out);
}